// Round 2
// baseline (762.508 us; speedup 1.0000x reference)
//
#include <hip/hip_runtime.h>
#include <math.h>

// SparseNet: conv1(2x2,200->16,pad(0,1)) * mask -> maskedpool 3x3/3 ->
// conv2(5x5,16->32,VALID) * pooledmask -> maskedpool 3x3/1 -> linear(32,2) -> softmax
// B=1024, H=W=21, Cin=200.
//
// ws layout:
//   h1   [1024*441*16] float   (28.9 MB) - conv1 output at active sites only
//   wl   [451584] int          (1.8 MB)  - global compacted worklist (b*441+p)
//   nact [1] int

#define NEGINF -1e30f
#define H1_ELEMS (1024 * 441 * 16)
#define WL_ELEMS (1024 * 441)

// ---------------- K0: compact active sites into a global worklist ----------------
__global__ __launch_bounds__(256) void compact_kernel(
    const int* __restrict__ mask,   // [1024,21,21]
    int* __restrict__ wl,
    int* __restrict__ nact)
{
    __shared__ unsigned short loc[441];
    __shared__ int cnt, base;
    const int b = blockIdx.x;
    const int t = threadIdx.x;
    if (t == 0) cnt = 0;
    __syncthreads();
    for (int p = t; p < 441; p += 256)
        if (mask[b * 441 + p] != 0) loc[atomicAdd(&cnt, 1)] = (unsigned short)p;
    __syncthreads();
    if (t == 0) base = atomicAdd(nact, cnt);
    __syncthreads();
    const int n = cnt, bs = base, off = b * 441;
    for (int k = t; k < n; k += 256) wl[bs + k] = off + loc[k];
}

// ---------------- K1: conv1 as worklist-GEMM, 2 sites x 16 oc per thread ----------------
// Weights in LDS (51.2 KB), broadcast reads amortized over 2 sites.
// Tap gating is branch-free: inactive/out-of-range taps multiply by 0 with the
// pointer redirected to the site's own (always-active, L1-hot) row.
__global__ __launch_bounds__(256, 4) void conv1_kernel(
    const float* __restrict__ x,     // [1024,21,21,200]
    const int*   __restrict__ mask,  // [1024,21,21]
    const float* __restrict__ W1,    // [2,2,200,16]
    const int*   __restrict__ wl,
    const int*   __restrict__ nact,
    float* __restrict__ h1)          // [1024,441,16]
{
    __shared__ float w1s[4 * 200 * 16];   // 51.2 KB, layout [tap][k][oc]

    {
        const float4* __restrict__ wg = (const float4*)W1;
        float4* wd = (float4*)w1s;
        for (int v = threadIdx.x; v < 3200; v += 256) wd[v] = wg[v];
    }
    __syncthreads();

    const int n = *nact;
    const int gtid = blockIdx.x * 256 + threadIdx.x;
    const int gstride = gridDim.x * 256;

    for (int pair = gtid * 2; pair < n; pair += gstride * 2) {
        const int iA = wl[pair];
        const int iB = wl[min(pair + 1, n - 1)];   // dup of a real site if tail; benign

        const int bA = iA / 441, pA = iA - bA * 441;
        const int bB = iB / 441, pB = iB - bB * 441;
        const int ia = pA / 21, ja = pA - ia * 21;
        const int ib = pB / 21, jb = pB - ib * 21;

        float accA[16], accB[16];
        #pragma unroll
        for (int c = 0; c < 16; ++c) { accA[c] = 0.0f; accB[c] = 0.0f; }

        #pragma unroll
        for (int tap = 0; tap < 4; ++tap) {
            const int di = tap >> 1, dj = tap & 1;

            const int iiA = ia + di, jjA = ja + dj;
            const bool vA = (iiA < 21) & (jjA < 21);
            const int qA = vA ? (iiA * 21 + jjA) : pA;
            const float mA = (vA && mask[bA * 441 + qA] != 0) ? 1.0f : 0.0f;
            const float4* __restrict__ pa = (const float4*)(x + (size_t)(bA * 441 + qA) * 200);

            const int iiB = ib + di, jjB = jb + dj;
            const bool vB = (iiB < 21) & (jjB < 21);
            const int qB = vB ? (iiB * 21 + jjB) : pB;
            const float mB = (vB && mask[bB * 441 + qB] != 0) ? 1.0f : 0.0f;
            const float4* __restrict__ pb = (const float4*)(x + (size_t)(bB * 441 + qB) * 200);

            const float4* wbase = ((const float4*)w1s) + tap * 800;

            #pragma unroll 2
            for (int k4 = 0; k4 < 50; ++k4) {
                float4 xa = pa[k4];
                float4 xb = pb[k4];
                xa.x *= mA; xa.y *= mA; xa.z *= mA; xa.w *= mA;
                xb.x *= mB; xb.y *= mB; xb.z *= mB; xb.w *= mB;
                const float4* wp = wbase + k4 * 16;
                #pragma unroll
                for (int q = 0; q < 4; ++q) {
                    const float xsa = (q == 0) ? xa.x : (q == 1) ? xa.y : (q == 2) ? xa.z : xa.w;
                    const float xsb = (q == 0) ? xb.x : (q == 1) ? xb.y : (q == 2) ? xb.z : xb.w;
                    const float4 w0 = wp[q * 4 + 0];
                    const float4 w1 = wp[q * 4 + 1];
                    const float4 w2 = wp[q * 4 + 2];
                    const float4 w3 = wp[q * 4 + 3];
                    accA[0]  = fmaf(xsa, w0.x, accA[0]);  accB[0]  = fmaf(xsb, w0.x, accB[0]);
                    accA[1]  = fmaf(xsa, w0.y, accA[1]);  accB[1]  = fmaf(xsb, w0.y, accB[1]);
                    accA[2]  = fmaf(xsa, w0.z, accA[2]);  accB[2]  = fmaf(xsb, w0.z, accB[2]);
                    accA[3]  = fmaf(xsa, w0.w, accA[3]);  accB[3]  = fmaf(xsb, w0.w, accB[3]);
                    accA[4]  = fmaf(xsa, w1.x, accA[4]);  accB[4]  = fmaf(xsb, w1.x, accB[4]);
                    accA[5]  = fmaf(xsa, w1.y, accA[5]);  accB[5]  = fmaf(xsb, w1.y, accB[5]);
                    accA[6]  = fmaf(xsa, w1.z, accA[6]);  accB[6]  = fmaf(xsb, w1.z, accB[6]);
                    accA[7]  = fmaf(xsa, w1.w, accA[7]);  accB[7]  = fmaf(xsb, w1.w, accB[7]);
                    accA[8]  = fmaf(xsa, w2.x, accA[8]);  accB[8]  = fmaf(xsb, w2.x, accB[8]);
                    accA[9]  = fmaf(xsa, w2.y, accA[9]);  accB[9]  = fmaf(xsb, w2.y, accB[9]);
                    accA[10] = fmaf(xsa, w2.z, accA[10]); accB[10] = fmaf(xsb, w2.z, accB[10]);
                    accA[11] = fmaf(xsa, w2.w, accA[11]); accB[11] = fmaf(xsb, w2.w, accB[11]);
                    accA[12] = fmaf(xsa, w3.x, accA[12]); accB[12] = fmaf(xsb, w3.x, accB[12]);
                    accA[13] = fmaf(xsa, w3.y, accA[13]); accB[13] = fmaf(xsb, w3.y, accB[13]);
                    accA[14] = fmaf(xsa, w3.z, accA[14]); accB[14] = fmaf(xsb, w3.z, accB[14]);
                    accA[15] = fmaf(xsa, w3.w, accA[15]); accB[15] = fmaf(xsb, w3.w, accB[15]);
                }
            }
        }

        float4* dA = (float4*)(h1 + (size_t)iA * 16);
        dA[0] = make_float4(accA[0],  accA[1],  accA[2],  accA[3]);
        dA[1] = make_float4(accA[4],  accA[5],  accA[6],  accA[7]);
        dA[2] = make_float4(accA[8],  accA[9],  accA[10], accA[11]);
        dA[3] = make_float4(accA[12], accA[13], accA[14], accA[15]);
        float4* dB = (float4*)(h1 + (size_t)iB * 16);
        dB[0] = make_float4(accB[0],  accB[1],  accB[2],  accB[3]);
        dB[1] = make_float4(accB[4],  accB[5],  accB[6],  accB[7]);
        dB[2] = make_float4(accB[8],  accB[9],  accB[10], accB[11]);
        dB[3] = make_float4(accB[12], accB[13], accB[14], accB[15]);
    }
}

// ---------------- K2: pool1 + conv2 + pool2 + linear + softmax (fused tail) ----------------
__global__ __launch_bounds__(256) void tail_kernel(
    const float* __restrict__ h1,    // [1024,441,16] (valid at active sites only)
    const int*   __restrict__ mask,  // [1024,21,21]
    const float* __restrict__ W2,    // [5,5,16,32]
    const float* __restrict__ Wlin,  // [32,2]
    const float* __restrict__ blin,  // [2]
    float* __restrict__ out)         // [1024,2]
{
    __shared__ float h1s[441][16];
    __shared__ unsigned char msk[441];
    __shared__ float h2s[49][16];
    __shared__ float m2s[49];
    __shared__ float hc[9][32];
    __shared__ float m3s[9];
    __shared__ float h4[32];

    const int b = blockIdx.x;
    const int t = threadIdx.x;

    for (int p = t; p < 441; p += 256) {
        const int mv = mask[b * 441 + p];
        msk[p] = (unsigned char)(mv != 0);
        if (mv != 0) {
            const float4* __restrict__ src = (const float4*)(h1 + (size_t)(b * 441 + p) * 16);
            float4* dst = (float4*)&h1s[p][0];
            dst[0] = src[0]; dst[1] = src[1]; dst[2] = src[2]; dst[3] = src[3];
        }
    }
    __syncthreads();

    // masked maxpool 3x3/3: 21x21 -> 7x7
    for (int t2 = t; t2 < 784; t2 += 256) {
        const int cell = t2 >> 4;
        const int ch   = t2 & 15;
        const int pr = cell / 7, pc = cell - pr * 7;
        float best = NEGINF;
        bool any = false;
        #pragma unroll
        for (int r = 0; r < 3; ++r) {
            #pragma unroll
            for (int c = 0; c < 3; ++c) {
                const int s = (pr * 3 + r) * 21 + (pc * 3 + c);
                if (msk[s]) { any = true; best = fmaxf(best, h1s[s][ch]); }
            }
        }
        h2s[cell][ch] = any ? best : 0.0f;
        if (ch == 0) m2s[cell] = any ? 1.0f : 0.0f;
    }
    __syncthreads();

    // conv2: 7x7 -> 3x3, 16 -> 32 channels; gate by 5x5 mask-pool
    for (int t2 = t; t2 < 288; t2 += 256) {
        const int cell = t2 >> 5;
        const int oc   = t2 & 31;
        const int ci = cell / 3, cj = cell - ci * 3;
        float acc = 0.0f;
        float mm = 0.0f;
        #pragma unroll
        for (int di = 0; di < 5; ++di) {
            #pragma unroll
            for (int dj = 0; dj < 5; ++dj) {
                const int s = (ci + di) * 7 + (cj + dj);
                mm = fmaxf(mm, m2s[s]);
                const float* __restrict__ wrow = W2 + ((di * 5 + dj) * 16) * 32 + oc;
                #pragma unroll
                for (int c = 0; c < 16; ++c)
                    acc = fmaf(h2s[s][c], wrow[c * 32], acc);
            }
        }
        hc[cell][oc] = (mm > 0.0f) ? acc : 0.0f;
        if (oc == 0) m3s[cell] = mm;
    }
    __syncthreads();

    // final masked maxpool 3x3/1 on 3x3 -> 1x1
    if (t < 32) {
        float best = NEGINF;
        bool any = false;
        #pragma unroll
        for (int cell = 0; cell < 9; ++cell) {
            if (m3s[cell] > 0.0f) { any = true; best = fmaxf(best, hc[cell][t]); }
        }
        h4[t] = any ? best : 0.0f;
    }
    __syncthreads();

    if (t == 0) {
        float l0 = blin[0], l1 = blin[1];
        #pragma unroll
        for (int c = 0; c < 32; ++c) {
            l0 = fmaf(h4[c], Wlin[c * 2 + 0], l0);
            l1 = fmaf(h4[c], Wlin[c * 2 + 1], l1);
        }
        const float mx = fmaxf(l0, l1);
        const float e0 = expf(l0 - mx);
        const float e1 = expf(l1 - mx);
        const float inv = 1.0f / (e0 + e1);
        out[b * 2 + 0] = e0 * inv;
        out[b * 2 + 1] = e1 * inv;
    }
}

extern "C" void kernel_launch(void* const* d_in, const int* in_sizes, int n_in,
                              void* d_out, int out_size, void* d_ws, size_t ws_size,
                              hipStream_t stream) {
    const float* x    = (const float*)d_in[0];
    const int*   mask = (const int*)d_in[1];
    const float* W1   = (const float*)d_in[2];
    const float* W2   = (const float*)d_in[3];
    const float* Wlin = (const float*)d_in[4];
    const float* blin = (const float*)d_in[5];
    float* out = (float*)d_out;

    float* h1   = (float*)d_ws;
    int*   wl   = (int*)(h1 + H1_ELEMS);
    int*   nact = wl + WL_ELEMS;

    hipMemsetAsync(nact, 0, sizeof(int), stream);
    compact_kernel<<<1024, 256, 0, stream>>>(mask, wl, nact);
    conv1_kernel<<<512, 256, 0, stream>>>(x, mask, W1, wl, nact, h1);
    tail_kernel<<<1024, 256, 0, stream>>>(h1, mask, W2, Wlin, blin, out);
}